// Round 6
// baseline (648.507 us; speedup 1.0000x reference)
//
#include <hip/hip_runtime.h>
#include <hip/hip_fp16.h>

#define FEAT   64
#define BSHIFT 8                 // 256 dst-nodes per bucket
#define BNODES 256
#define MAXB   512               // supports N <= 131072
#define CHUNK  4096              // edges per partition block
#define TNODES 64                // nodes per node-transform block

// ---------------- fp32 -> fp16 conversion ----------------
__global__ __launch_bounds__(256) void tohalf_kernel(
    const float* __restrict__ in, __half* __restrict__ out, int n4)
{
    int i = blockIdx.x * 256 + threadIdx.x;
    if (i >= n4) return;
    float4 v = ((const float4*)in)[i];
    union { uint2 u; __half2 h2[2]; } r;
    r.h2[0] = __floats2half2_rn(v.x, v.y);
    r.h2[1] = __floats2half2_rn(v.z, v.w);
    ((uint2*)out)[i] = r.u;
}

// ---------------- Pass 1: per-bucket edge counts ----------------
__global__ __launch_bounds__(256) void bucket_count_kernel(
    const int* __restrict__ dst, int* __restrict__ bcnt, int E)
{
    __shared__ int cnt[MAXB];
    for (int i = threadIdx.x; i < MAXB; i += 256) cnt[i] = 0;
    __syncthreads();
    int base = blockIdx.x * CHUNK;
    for (int i = threadIdx.x; i < CHUNK; i += 256) {
        int e = base + i;
        if (e < E) atomicAdd(&cnt[dst[e] >> BSHIFT], 1);
    }
    __syncthreads();
    for (int i = threadIdx.x; i < MAXB; i += 256)
        if (cnt[i]) atomicAdd(&bcnt[i], cnt[i]);
}

// ---------------- Pass 2: scan bucket counts (1 block) ----------------
__global__ __launch_bounds__(512) void bucket_scan_kernel(
    const int* __restrict__ bcnt, int* __restrict__ boff, int* __restrict__ bcur,
    int NB, int E)
{
    __shared__ int s[512];
    int v = (threadIdx.x < (unsigned)NB) ? bcnt[threadIdx.x] : 0;
    s[threadIdx.x] = v;
    __syncthreads();
    for (int off = 1; off < 512; off <<= 1) {
        int t = (threadIdx.x >= (unsigned)off) ? s[threadIdx.x - off] : 0;
        __syncthreads();
        s[threadIdx.x] += t;
        __syncthreads();
    }
    if (threadIdx.x < (unsigned)NB) {
        int ex = s[threadIdx.x] - v;
        boff[threadIdx.x] = ex;
        bcur[threadIdx.x] = ex;
    }
    if (threadIdx.x == 0) boff[NB] = E;
}

// ---------------- Pass 3: partition edges into buckets ----------------
// Output word: src | (local_dst << 20)
__global__ __launch_bounds__(256) void partition_kernel(
    const int* __restrict__ src, const int* __restrict__ dst,
    int* __restrict__ bcur, int* __restrict__ pedge, int E)
{
    __shared__ int cnt[MAXB];
    __shared__ int sa[MAXB], sb[MAXB];
    __shared__ int gb[MAXB];
    __shared__ int lcur[MAXB];
    __shared__ int stage[CHUNK];
    __shared__ int tgt[CHUNK];

    for (int i = threadIdx.x; i < MAXB; i += 256) cnt[i] = 0;
    __syncthreads();

    int base = blockIdx.x * CHUNK;
    int vals[16];
    int bs[16];
#pragma unroll
    for (int i = 0; i < 16; i++) {
        int e = base + threadIdx.x + i * 256;
        bs[i] = -1;
        if (e < E) {
            int s_ = src[e];
            int d_ = dst[e];
            int b  = d_ >> BSHIFT;
            bs[i]  = b;
            vals[i] = s_ | ((d_ & (BNODES - 1)) << 20);
            atomicAdd(&cnt[b], 1);
        }
    }
    __syncthreads();

    for (int i = threadIdx.x; i < MAXB; i += 256) sa[i] = cnt[i];
    __syncthreads();
    int* cur = sa; int* nxt = sb;
    for (int off = 1; off < MAXB; off <<= 1) {
        for (int i = threadIdx.x; i < MAXB; i += 256)
            nxt[i] = cur[i] + ((i >= off) ? cur[i - off] : 0);
        __syncthreads();
        int* tmp = cur; cur = nxt; nxt = tmp;
    }
    for (int i = threadIdx.x; i < MAXB; i += 256) {
        int c = cnt[i];
        int lo = cur[i] - c;
        int gbase = c ? atomicAdd(&bcur[i], c) : 0;
        gb[i]   = gbase - lo;
        lcur[i] = lo;
    }
    __syncthreads();

#pragma unroll
    for (int i = 0; i < 16; i++) {
        if (bs[i] >= 0) {
            int pos = atomicAdd(&lcur[bs[i]], 1);
            stage[pos] = vals[i];
            tgt[pos]   = gb[bs[i]];
        }
    }
    __syncthreads();

    int cn = min(CHUNK, E - base);
    for (int i = threadIdx.x; i < cn; i += 256)
        pedge[tgt[i] + i] = stage[i];
}

// ---------------- Pass 4: per-bucket CSR build ----------------
__global__ __launch_bounds__(256) void buildcsr_kernel(
    const int* __restrict__ pedge, const int* __restrict__ boff,
    int* __restrict__ rowptr, int* __restrict__ csr_src, int N, int NB)
{
    __shared__ int hist[BNODES];
    __shared__ int scn[BNODES];
    __shared__ int lcur[BNODES];
    int b = blockIdx.x;
    int beg = boff[b], end = boff[b + 1];

    hist[threadIdx.x] = 0;
    __syncthreads();
    for (int e = beg + (int)threadIdx.x; e < end; e += 256)
        atomicAdd(&hist[pedge[e] >> 20], 1);
    __syncthreads();

    int v = hist[threadIdx.x];
    scn[threadIdx.x] = v;
    __syncthreads();
    for (int off = 1; off < 256; off <<= 1) {
        int t = (threadIdx.x >= (unsigned)off) ? scn[threadIdx.x - off] : 0;
        __syncthreads();
        scn[threadIdx.x] += t;
        __syncthreads();
    }
    int excl = scn[threadIdx.x] - v;

    int node = (b << BSHIFT) + threadIdx.x;
    if (node < N) rowptr[node] = beg + excl;
    if (b == NB - 1 && threadIdx.x == 0) rowptr[N] = boff[NB];
    lcur[threadIdx.x] = excl;
    __syncthreads();

    for (int e = beg + (int)threadIdx.x; e < end; e += 256) {
        int p  = pedge[e];
        int ld = p >> 20;
        int pos = atomicAdd(&lcur[ld], 1);
        csr_src[beg + pos] = p & 0xFFFFF;
    }
}

// ---------------- Aggregation: gather-mean over fp16 rows ----------------
// Wave per node; lanes = 8 edge-groups x 8 half8-slots (16B). One load
// instruction serves 8 edges. fp32 accumulate; xor-shuffle reduce.
__global__ __launch_bounds__(256) void gather_kernel(
    const __half* __restrict__ x, const int* __restrict__ rowptr,
    const int* __restrict__ csr_src, float* __restrict__ mean, int N)
{
    int node = blockIdx.x * 4 + (threadIdx.x >> 6);
    if (node >= N) return;
    int lane = threadIdx.x & 63;
    int g  = lane >> 3;          // edge group 0..7
    int s8 = lane & 7;           // half8 slot within row (16 B)
    int beg = rowptr[node], end = rowptr[node + 1];

    float acc[8] = {0.f,0.f,0.f,0.f,0.f,0.f,0.f,0.f};
    int e = beg + g;
    for (; e + 8 < end; e += 16) {           // 2 rows in flight per group
        int i0 = csr_src[e];
        int i1 = csr_src[e + 8];
        union { uint4 u; __half2 h2[4]; } r0, r1;
        r0.u = ((const uint4*)(x + (size_t)i0 * FEAT))[s8];
        r1.u = ((const uint4*)(x + (size_t)i1 * FEAT))[s8];
#pragma unroll
        for (int t = 0; t < 4; t++) {
            float2 f0 = __half22float2(r0.h2[t]);
            float2 f1 = __half22float2(r1.h2[t]);
            acc[2*t]   += f0.x + f1.x;
            acc[2*t+1] += f0.y + f1.y;
        }
    }
    if (e < end) {
        int i0 = csr_src[e];
        union { uint4 u; __half2 h2[4]; } r0;
        r0.u = ((const uint4*)(x + (size_t)i0 * FEAT))[s8];
#pragma unroll
        for (int t = 0; t < 4; t++) {
            float2 f0 = __half22float2(r0.h2[t]);
            acc[2*t]   += f0.x;
            acc[2*t+1] += f0.y;
        }
    }
    // reduce across 8 edge groups (lane bits 3,4,5)
#pragma unroll
    for (int mask = 8; mask <= 32; mask <<= 1)
#pragma unroll
        for (int t = 0; t < 8; t++)
            acc[t] += __shfl_xor(acc[t], mask, 64);
    if (g == 0) {
        float inv = 1.0f / fmaxf((float)(end - beg), 1.0f);
        float* mrow = mean + (size_t)node * FEAT;
        float4 lo = make_float4(acc[0]*inv, acc[1]*inv, acc[2]*inv, acc[3]*inv);
        float4 hi = make_float4(acc[4]*inv, acc[5]*inv, acc[6]*inv, acc[7]*inv);
        ((float4*)mrow)[2*s8]     = lo;      // 8 lanes x 32 B = 256 B row
        ((float4*)mrow)[2*s8 + 1] = hi;
    }
}

// ---------------- Fused node transform: relu(sage) then linear ----------------
// Block = 64 nodes, 4 waves; wave w computes output feats [16w,16w+16)
// (lane = node, j wave-uniform -> scalar weight loads). Stage 1 result goes
// to LDS (stride FEAT+1: conflict-free), stage 2 reads it back, output staged
// again and flushed with lane = feature -> fully coalesced stores.
__global__ __launch_bounds__(256) void sage_lin_kernel(
    const float* __restrict__ mean,
    const float* __restrict__ xin_f, const __half* __restrict__ xin_h,
    const float* __restrict__ w_l, const float* __restrict__ b_l,
    const float* __restrict__ w_r,
    const float* __restrict__ w2, const float* __restrict__ b2,
    float* __restrict__ out_f, __half* __restrict__ out_h,
    int n, int relu_out)
{
    __shared__ float s1[TNODES][FEAT + 1];
    int wave = threadIdx.x >> 6;
    int lane = threadIdx.x & 63;
    int base = blockIdx.x * TNODES;
    int node_c = min(base + lane, n - 1);
    int j0 = __builtin_amdgcn_readfirstlane(wave * 16);

    float acc[16];
#pragma unroll
    for (int j = 0; j < 16; j++) acc[j] = b_l[j0 + j];

    const float4* mv = (const float4*)(mean + (size_t)node_c * FEAT);
#pragma unroll
    for (int q = 0; q < FEAT / 4; q++) {
        float4 m4 = mv[q];
        float xk[4];
        if (xin_h) {
            union { uint2 u; __half2 h2[2]; } r;
            r.u = ((const uint2*)(xin_h + (size_t)node_c * FEAT))[q];
            float2 a = __half22float2(r.h2[0]);
            float2 b = __half22float2(r.h2[1]);
            xk[0] = a.x; xk[1] = a.y; xk[2] = b.x; xk[3] = b.y;
        } else {
            float4 x4 = ((const float4*)(xin_f + (size_t)node_c * FEAT))[q];
            xk[0] = x4.x; xk[1] = x4.y; xk[2] = x4.z; xk[3] = x4.w;
        }
        float mk[4] = {m4.x, m4.y, m4.z, m4.w};
#pragma unroll
        for (int kk = 0; kk < 4; kk++) {
            int k = q * 4 + kk;
            const float* wl = w_l + k * FEAT + j0;   // uniform -> s_load
            const float* wr = w_r + k * FEAT + j0;
#pragma unroll
            for (int j = 0; j < 16; j++)
                acc[j] += mk[kk] * wl[j] + xk[kk] * wr[j];
        }
    }
#pragma unroll
    for (int j = 0; j < 16; j++)
        s1[lane][j0 + j] = fmaxf(acc[j], 0.0f);      // relu(sage)
    __syncthreads();

    float acc2[16];
#pragma unroll
    for (int j = 0; j < 16; j++) acc2[j] = b2[j0 + j];
#pragma unroll
    for (int k = 0; k < FEAT; k++) {
        float xk = s1[lane][k];                      // bank = (lane+k)%32, free
        const float* wp = w2 + k * FEAT + j0;        // uniform -> s_load
#pragma unroll
        for (int j = 0; j < 16; j++) acc2[j] += xk * wp[j];
    }
    __syncthreads();
#pragma unroll
    for (int j = 0; j < 16; j++)
        s1[lane][j0 + j] = relu_out ? fmaxf(acc2[j], 0.0f) : acc2[j];
    __syncthreads();

#pragma unroll
    for (int r = 0; r < 16; r++) {
        int row = wave * 16 + r;
        int gn = base + row;
        if (gn < n) {
            float v = s1[row][lane];
            if (out_h) out_h[(size_t)gn * FEAT + lane] = __float2half(v);
            else       out_f[(size_t)gn * FEAT + lane] = v;
        }
    }
}

extern "C" void kernel_launch(void* const* d_in, const int* in_sizes, int n_in,
                              void* d_out, int out_size, void* d_ws, size_t ws_size,
                              hipStream_t stream) {
    const float* h      = (const float*)d_in[0];
    const int*   ei     = (const int*)d_in[1];
    const float* w1_l   = (const float*)d_in[2];
    const float* b1_l   = (const float*)d_in[3];
    const float* w1_r   = (const float*)d_in[4];
    const float* w_lin1 = (const float*)d_in[5];
    const float* b_lin1 = (const float*)d_in[6];
    const float* w2_l   = (const float*)d_in[7];
    const float* b2_l   = (const float*)d_in[8];
    const float* w2_r   = (const float*)d_in[9];
    const float* w_lin2 = (const float*)d_in[10];
    const float* b_lin2 = (const float*)d_in[11];

    const int N = in_sizes[0] / FEAT;
    const int E = in_sizes[1] / 2;
    const int* src  = ei;
    const int* dst_ = ei + E;

    const int NB = (N + BNODES - 1) >> BSHIFT;
    const int PB = (E + CHUNK - 1) / CHUNK;
    const int tblk = (N + TNODES - 1) / TNODES;
    const int gblk = (N + 3) / 4;

    // Workspace (float-indexed):
    // bcnt | boff | bcur | rowptr[N+1] | csr[E] | h16[N*32] | x2h[N*32] | mean[N*64]
    // pedge aliased onto mean (dead after buildcsr).
    size_t off = 0;
    int* bcnt   = (int*)d_ws + off; off += MAXB;
    int* boff   = (int*)d_ws + off; off += MAXB + 1;
    int* bcur   = (int*)d_ws + off; off += MAXB;
    off = (off + 3) & ~(size_t)3;
    int* rowptr = (int*)d_ws + off; off += (size_t)N + 1;
    off = (off + 3) & ~(size_t)3;
    int* csr    = (int*)d_ws + off; off += (size_t)E;
    off = (off + 3) & ~(size_t)3;
    __half* h16 = (__half*)((int*)d_ws + off); off += (size_t)N * FEAT / 2;
    __half* x2h = (__half*)((int*)d_ws + off); off += (size_t)N * FEAT / 2;
    float* mean = (float*)d_ws + off;
    int* pedge  = (int*)mean;

    // ---- preprocessing (once, reused by both conv layers) ----
    hipMemsetAsync(bcnt, 0, MAXB * sizeof(int), stream);
    tohalf_kernel<<<(N * FEAT / 4 + 255) / 256, 256, 0, stream>>>(h, h16, N * FEAT / 4);
    bucket_count_kernel<<<PB, 256, 0, stream>>>(dst_, bcnt, E);
    bucket_scan_kernel<<<1, 512, 0, stream>>>(bcnt, boff, bcur, NB, E);
    partition_kernel<<<PB, 256, 0, stream>>>(src, dst_, bcur, pedge, E);
    buildcsr_kernel<<<NB, 256, 0, stream>>>(pedge, boff, rowptr, csr, N, NB);

    // ---- Layer 1: conv1 + lin1 (self path reads fp32 h; output fp16) ----
    gather_kernel<<<gblk, 256, 0, stream>>>(h16, rowptr, csr, mean, N);
    sage_lin_kernel<<<tblk, 256, 0, stream>>>(mean, h, (const __half*)nullptr,
                                              w1_l, b1_l, w1_r, w_lin1, b_lin1,
                                              (float*)nullptr, x2h, N, 1);

    // ---- Layer 2: conv2 + lin2 (self path reads fp16 x2; output fp32) ----
    gather_kernel<<<gblk, 256, 0, stream>>>(x2h, rowptr, csr, mean, N);
    sage_lin_kernel<<<tblk, 256, 0, stream>>>(mean, (const float*)nullptr, x2h,
                                              w2_l, b2_l, w2_r, w_lin2, b_lin2,
                                              (float*)d_out, (__half*)nullptr, N, 0);
}

// Round 7
// 305.040 us; speedup vs baseline: 2.1260x; 2.1260x over previous
//
#include <hip/hip_runtime.h>
#include <hip/hip_fp16.h>

#define FEAT   64
#define BSHIFT 8                 // 256 dst-nodes per bucket
#define BNODES 256
#define MAXB   512               // supports N <= 131072
#define CHUNK  4096              // edges per partition block

typedef _Float16 half8 __attribute__((ext_vector_type(8)));
typedef float  float4v __attribute__((ext_vector_type(4)));

// ---------------- fp32 -> fp16 conversion ----------------
__global__ __launch_bounds__(256) void tohalf_kernel(
    const float* __restrict__ in, __half* __restrict__ out, int n4)
{
    int i = blockIdx.x * 256 + threadIdx.x;
    if (i >= n4) return;
    float4 v = ((const float4*)in)[i];
    union { uint2 u; __half2 h2[2]; } r;
    r.h2[0] = __floats2half2_rn(v.x, v.y);
    r.h2[1] = __floats2half2_rn(v.z, v.w);
    ((uint2*)out)[i] = r.u;
}

// ---------------- weight prep: fp32 [in][out] -> f16 transposed [out][in] ----------------
__global__ __launch_bounds__(256) void prep_weights_kernel(
    const float* w0, const float* w1, const float* w2,
    const float* w3, const float* w4, const float* w5,
    __half* __restrict__ dst)
{
    int m = blockIdx.x >> 4;                         // matrix 0..5
    int idx = ((blockIdx.x & 15) << 8) | threadIdx.x; // 0..4095
    const float* src = m==0?w0 : m==1?w1 : m==2?w2 : m==3?w3 : m==4?w4 : w5;
    int o = idx >> 6, i = idx & 63;
    dst[m * 4096 + o * 64 + i] = __float2half(src[i * 64 + o]);
}

// ---------------- Pass 1: per-bucket edge counts ----------------
__global__ __launch_bounds__(256) void bucket_count_kernel(
    const int* __restrict__ dst, int* __restrict__ bcnt, int E)
{
    __shared__ int cnt[MAXB];
    for (int i = threadIdx.x; i < MAXB; i += 256) cnt[i] = 0;
    __syncthreads();
    int base = blockIdx.x * CHUNK;
    for (int i = threadIdx.x; i < CHUNK; i += 256) {
        int e = base + i;
        if (e < E) atomicAdd(&cnt[dst[e] >> BSHIFT], 1);
    }
    __syncthreads();
    for (int i = threadIdx.x; i < MAXB; i += 256)
        if (cnt[i]) atomicAdd(&bcnt[i], cnt[i]);
}

// ---------------- Pass 2: scan bucket counts (1 block) ----------------
__global__ __launch_bounds__(512) void bucket_scan_kernel(
    const int* __restrict__ bcnt, int* __restrict__ boff, int* __restrict__ bcur,
    int NB, int E)
{
    __shared__ int s[512];
    int v = (threadIdx.x < (unsigned)NB) ? bcnt[threadIdx.x] : 0;
    s[threadIdx.x] = v;
    __syncthreads();
    for (int off = 1; off < 512; off <<= 1) {
        int t = (threadIdx.x >= (unsigned)off) ? s[threadIdx.x - off] : 0;
        __syncthreads();
        s[threadIdx.x] += t;
        __syncthreads();
    }
    if (threadIdx.x < (unsigned)NB) {
        int ex = s[threadIdx.x] - v;
        boff[threadIdx.x] = ex;
        bcur[threadIdx.x] = ex;
    }
    if (threadIdx.x == 0) boff[NB] = E;
}

// ---------------- Pass 3: partition edges into buckets ----------------
// Output word: src | (local_dst << 20)
__global__ __launch_bounds__(256) void partition_kernel(
    const int* __restrict__ src, const int* __restrict__ dst,
    int* __restrict__ bcur, int* __restrict__ pedge, int E)
{
    __shared__ int cnt[MAXB];
    __shared__ int sa[MAXB], sb[MAXB];
    __shared__ int gb[MAXB];
    __shared__ int lcur[MAXB];
    __shared__ int stage[CHUNK];
    __shared__ int tgt[CHUNK];

    for (int i = threadIdx.x; i < MAXB; i += 256) cnt[i] = 0;
    __syncthreads();

    int base = blockIdx.x * CHUNK;
    int vals[16];
    int bs[16];
#pragma unroll
    for (int i = 0; i < 16; i++) {
        int e = base + threadIdx.x + i * 256;
        bs[i] = -1;
        if (e < E) {
            int s_ = src[e];
            int d_ = dst[e];
            int b  = d_ >> BSHIFT;
            bs[i]  = b;
            vals[i] = s_ | ((d_ & (BNODES - 1)) << 20);
            atomicAdd(&cnt[b], 1);
        }
    }
    __syncthreads();

    for (int i = threadIdx.x; i < MAXB; i += 256) sa[i] = cnt[i];
    __syncthreads();
    int* cur = sa; int* nxt = sb;
    for (int off = 1; off < MAXB; off <<= 1) {
        for (int i = threadIdx.x; i < MAXB; i += 256)
            nxt[i] = cur[i] + ((i >= off) ? cur[i - off] : 0);
        __syncthreads();
        int* tmp = cur; cur = nxt; nxt = tmp;
    }
    for (int i = threadIdx.x; i < MAXB; i += 256) {
        int c = cnt[i];
        int lo = cur[i] - c;
        int gbase = c ? atomicAdd(&bcur[i], c) : 0;
        gb[i]   = gbase - lo;
        lcur[i] = lo;
    }
    __syncthreads();

#pragma unroll
    for (int i = 0; i < 16; i++) {
        if (bs[i] >= 0) {
            int pos = atomicAdd(&lcur[bs[i]], 1);
            stage[pos] = vals[i];
            tgt[pos]   = gb[bs[i]];
        }
    }
    __syncthreads();

    int cn = min(CHUNK, E - base);
    for (int i = threadIdx.x; i < cn; i += 256)
        pedge[tgt[i] + i] = stage[i];
}

// ---------------- Pass 4: per-bucket CSR build ----------------
__global__ __launch_bounds__(256) void buildcsr_kernel(
    const int* __restrict__ pedge, const int* __restrict__ boff,
    int* __restrict__ rowptr, int* __restrict__ csr_src, int N, int NB)
{
    __shared__ int hist[BNODES];
    __shared__ int scn[BNODES];
    __shared__ int lcur[BNODES];
    int b = blockIdx.x;
    int beg = boff[b], end = boff[b + 1];

    hist[threadIdx.x] = 0;
    __syncthreads();
    for (int e = beg + (int)threadIdx.x; e < end; e += 256)
        atomicAdd(&hist[pedge[e] >> 20], 1);
    __syncthreads();

    int v = hist[threadIdx.x];
    scn[threadIdx.x] = v;
    __syncthreads();
    for (int off = 1; off < 256; off <<= 1) {
        int t = (threadIdx.x >= (unsigned)off) ? scn[threadIdx.x - off] : 0;
        __syncthreads();
        scn[threadIdx.x] += t;
        __syncthreads();
    }
    int excl = scn[threadIdx.x] - v;

    int node = (b << BSHIFT) + threadIdx.x;
    if (node < N) rowptr[node] = beg + excl;
    if (b == NB - 1 && threadIdx.x == 0) rowptr[N] = boff[NB];
    lcur[threadIdx.x] = excl;
    __syncthreads();

    for (int e = beg + (int)threadIdx.x; e < end; e += 256) {
        int p  = pedge[e];
        int ld = p >> 20;
        int pos = atomicAdd(&lcur[ld], 1);
        csr_src[beg + pos] = p & 0xFFFFF;
    }
}

// ---------------- Aggregation: gather-mean over fp16 rows, fp16 out ----------------
// Wave per node; lanes = 8 edge-groups x 8 half8-slots (16B). fp32 accumulate.
__global__ __launch_bounds__(256) void gather_kernel(
    const __half* __restrict__ x, const int* __restrict__ rowptr,
    const int* __restrict__ csr_src, __half* __restrict__ mean, int N)
{
    int node = blockIdx.x * 4 + (threadIdx.x >> 6);
    if (node >= N) return;
    int lane = threadIdx.x & 63;
    int g  = lane >> 3;          // edge group 0..7
    int s8 = lane & 7;           // half8 slot within row (16 B)
    int beg = rowptr[node], end = rowptr[node + 1];

    float acc[8] = {0.f,0.f,0.f,0.f,0.f,0.f,0.f,0.f};
    int e = beg + g;
    for (; e + 8 < end; e += 16) {
        int i0 = csr_src[e];
        int i1 = csr_src[e + 8];
        union { uint4 u; __half2 h2[4]; } r0, r1;
        r0.u = ((const uint4*)(x + (size_t)i0 * FEAT))[s8];
        r1.u = ((const uint4*)(x + (size_t)i1 * FEAT))[s8];
#pragma unroll
        for (int t = 0; t < 4; t++) {
            float2 f0 = __half22float2(r0.h2[t]);
            float2 f1 = __half22float2(r1.h2[t]);
            acc[2*t]   += f0.x + f1.x;
            acc[2*t+1] += f0.y + f1.y;
        }
    }
    if (e < end) {
        int i0 = csr_src[e];
        union { uint4 u; __half2 h2[4]; } r0;
        r0.u = ((const uint4*)(x + (size_t)i0 * FEAT))[s8];
#pragma unroll
        for (int t = 0; t < 4; t++) {
            float2 f0 = __half22float2(r0.h2[t]);
            acc[2*t]   += f0.x;
            acc[2*t+1] += f0.y;
        }
    }
#pragma unroll
    for (int mask = 8; mask <= 32; mask <<= 1)
#pragma unroll
        for (int t = 0; t < 8; t++)
            acc[t] += __shfl_xor(acc[t], mask, 64);
    if (g == 0) {
        float inv = 1.0f / fmaxf((float)(end - beg), 1.0f);
        union { uint4 u; __half2 h2[4]; } o;
        o.h2[0] = __floats2half2_rn(acc[0]*inv, acc[1]*inv);
        o.h2[1] = __floats2half2_rn(acc[2]*inv, acc[3]*inv);
        o.h2[2] = __floats2half2_rn(acc[4]*inv, acc[5]*inv);
        o.h2[3] = __floats2half2_rn(acc[6]*inv, acc[7]*inv);
        ((uint4*)(mean + (size_t)node * FEAT))[s8] = o.u;   // 8 lanes x 16B = 128B row
    }
}

// ---------------- Fused node transform via MFMA ----------------
// Block = 64 nodes, 4 waves; wave w owns rows [16w,16w+16) of the block.
// Stage 1: relu(mean@Wl + self@Wr + b1) -> LDS (A-layout re-entry).
// Stage 2: (stage1)@W2 + b2, optional relu, direct C-layout global store.
// Weights are f16 TRANSPOSED [out][in] so B-frags are contiguous 16B loads.
// Layouts (m89/m91-verified): A[m=lane&15][k=quad*8+j], B[k=quad*8+j][n=lane&15],
// C col=lane&15, row=quad*4+reg.
__global__ __launch_bounds__(256) void node_mfma_kernel(
    const __half* __restrict__ mean16, const __half* __restrict__ self16,
    const __half* __restrict__ wlT, const __half* __restrict__ wrT,
    const __half* __restrict__ w2T,
    const float* __restrict__ b1, const float* __restrict__ b2,
    float* __restrict__ out_f, __half* __restrict__ out_h,
    int n, int relu_out)
{
    __shared__ _Float16 s1[64][68];     // pad 68: 2-way (free) writes, ~4-way reads
    int wave = threadIdx.x >> 6;
    int lane = threadIdx.x & 63;
    int r = lane & 15;                  // A row / B-C col
    int q = lane >> 4;                  // quad
    int base = blockIdx.x * 64 + wave * 16;

    // ---- stage 1 ----
    int arow = min(base + r, n - 1);
    const half8* mrow = (const half8*)(mean16 + (size_t)arow * FEAT);
    const half8* xrow = (const half8*)(self16 + (size_t)arow * FEAT);
    half8 Am0 = mrow[q], Am1 = mrow[4 + q];
    half8 Ax0 = xrow[q], Ax1 = xrow[4 + q];

    float4v acc[4];
#pragma unroll
    for (int c = 0; c < 4; c++) {
        float bv = b1[c * 16 + r];
        acc[c] = (float4v){bv, bv, bv, bv};
        const half8* bl = (const half8*)(wlT + (size_t)(c * 16 + r) * FEAT);
        const half8* br = (const half8*)(wrT + (size_t)(c * 16 + r) * FEAT);
        acc[c] = __builtin_amdgcn_mfma_f32_16x16x32_f16(Am0, bl[q],     acc[c], 0, 0, 0);
        acc[c] = __builtin_amdgcn_mfma_f32_16x16x32_f16(Am1, bl[4 + q], acc[c], 0, 0, 0);
        acc[c] = __builtin_amdgcn_mfma_f32_16x16x32_f16(Ax0, br[q],     acc[c], 0, 0, 0);
        acc[c] = __builtin_amdgcn_mfma_f32_16x16x32_f16(Ax1, br[4 + q], acc[c], 0, 0, 0);
    }
#pragma unroll
    for (int c = 0; c < 4; c++)
#pragma unroll
        for (int t = 0; t < 4; t++)
            s1[wave * 16 + q * 4 + t][c * 16 + r] = (_Float16)fmaxf(acc[c][t], 0.0f);
    __syncthreads();

    // ---- stage 2: A from LDS (row = lane&15 of this wave's tile) ----
    union { uint2 u2[2]; half8 h; } A2[2];
#pragma unroll
    for (int s = 0; s < 2; s++) {
        const _Float16* p = &s1[wave * 16 + r][s * 32 + q * 8];
        A2[s].u2[0] = *(const uint2*)p;         // rows 8B-aligned (stride 136B)
        A2[s].u2[1] = *(const uint2*)(p + 4);
    }

    float4v acc2[4];
#pragma unroll
    for (int c = 0; c < 4; c++) {
        float bv = b2[c * 16 + r];
        acc2[c] = (float4v){bv, bv, bv, bv};
        const half8* bw = (const half8*)(w2T + (size_t)(c * 16 + r) * FEAT);
        acc2[c] = __builtin_amdgcn_mfma_f32_16x16x32_f16(A2[0].h, bw[q],     acc2[c], 0, 0, 0);
        acc2[c] = __builtin_amdgcn_mfma_f32_16x16x32_f16(A2[1].h, bw[4 + q], acc2[c], 0, 0, 0);
    }

#pragma unroll
    for (int c = 0; c < 4; c++)
#pragma unroll
        for (int t = 0; t < 4; t++) {
            int gr = base + q * 4 + t;
            if (gr < n) {
                float v = acc2[c][t];
                if (relu_out) v = fmaxf(v, 0.0f);
                if (out_h) out_h[(size_t)gr * FEAT + c * 16 + r] = __float2half(v);
                else       out_f[(size_t)gr * FEAT + c * 16 + r] = v;
            }
        }
}

extern "C" void kernel_launch(void* const* d_in, const int* in_sizes, int n_in,
                              void* d_out, int out_size, void* d_ws, size_t ws_size,
                              hipStream_t stream) {
    const float* h      = (const float*)d_in[0];
    const int*   ei     = (const int*)d_in[1];
    const float* w1_l   = (const float*)d_in[2];
    const float* b1_l   = (const float*)d_in[3];
    const float* w1_r   = (const float*)d_in[4];
    const float* w_lin1 = (const float*)d_in[5];
    const float* b_lin1 = (const float*)d_in[6];
    const float* w2_l   = (const float*)d_in[7];
    const float* b2_l   = (const float*)d_in[8];
    const float* w2_r   = (const float*)d_in[9];
    const float* w_lin2 = (const float*)d_in[10];
    const float* b_lin2 = (const float*)d_in[11];

    const int N = in_sizes[0] / FEAT;
    const int E = in_sizes[1] / 2;
    const int* src  = ei;
    const int* dst_ = ei + E;

    const int NB = (N + BNODES - 1) >> BSHIFT;
    const int PB = (E + CHUNK - 1) / CHUNK;
    const int tblk = (N + 63) / 64;
    const int gblk = (N + 3) / 4;

    // Workspace (float-indexed):
    // bcnt | boff | bcur | rowptr[N+1] | csr[E] | h16[N*32] | x2h[N*32] | wT[6*2048] | mean16[N*32]
    // pedge aliased onto mean16 region (dead before gather).
    size_t off = 0;
    int* bcnt   = (int*)d_ws + off; off += MAXB;
    int* boff   = (int*)d_ws + off; off += MAXB + 1;
    int* bcur   = (int*)d_ws + off; off += MAXB;
    off = (off + 3) & ~(size_t)3;
    int* rowptr = (int*)d_ws + off; off += (size_t)N + 1;
    off = (off + 3) & ~(size_t)3;
    int* csr    = (int*)d_ws + off; off += (size_t)E;
    off = (off + 3) & ~(size_t)3;
    __half* h16 = (__half*)((int*)d_ws + off); off += (size_t)N * FEAT / 2;
    __half* x2h = (__half*)((int*)d_ws + off); off += (size_t)N * FEAT / 2;
    __half* wT  = (__half*)((int*)d_ws + off); off += 6 * 2048;
    __half* mean16 = (__half*)((int*)d_ws + off); off += (size_t)N * FEAT / 2;
    int* pedge  = (int*)mean16;

    // ---- preprocessing (once, reused by both conv layers) ----
    hipMemsetAsync(bcnt, 0, MAXB * sizeof(int), stream);
    tohalf_kernel<<<(N * FEAT / 4 + 255) / 256, 256, 0, stream>>>(h, h16, N * FEAT / 4);
    prep_weights_kernel<<<96, 256, 0, stream>>>(w1_l, w1_r, w_lin1, w2_l, w2_r, w_lin2, wT);
    bucket_count_kernel<<<PB, 256, 0, stream>>>(dst_, bcnt, E);
    bucket_scan_kernel<<<1, 512, 0, stream>>>(bcnt, boff, bcur, NB, E);
    partition_kernel<<<PB, 256, 0, stream>>>(src, dst_, bcur, pedge, E);
    buildcsr_kernel<<<NB, 256, 0, stream>>>(pedge, boff, rowptr, csr, N, NB);

    // ---- Layer 1: conv1 + lin1 (f16 in, f16 out) ----
    gather_kernel<<<gblk, 256, 0, stream>>>(h16, rowptr, csr, mean16, N);
    node_mfma_kernel<<<tblk, 256, 0, stream>>>(mean16, h16,
                                               wT + 0 * 4096, wT + 1 * 4096, wT + 2 * 4096,
                                               b1_l, b_lin1,
                                               (float*)nullptr, x2h, N, 1);

    // ---- Layer 2: conv2 + lin2 (f16 in, fp32 out) ----
    gather_kernel<<<gblk, 256, 0, stream>>>(x2h, rowptr, csr, mean16, N);
    node_mfma_kernel<<<tblk, 256, 0, stream>>>(mean16, x2h,
                                               wT + 3 * 4096, wT + 4 * 4096, wT + 5 * 4096,
                                               b2_l, b_lin2,
                                               (float*)d_out, (__half*)nullptr, N, 0);
}

// Round 8
// 304.879 us; speedup vs baseline: 2.1271x; 1.0005x over previous
//
#include <hip/hip_runtime.h>
#include <hip/hip_fp16.h>

#define FEAT   64
#define BSHIFT 8                 // 256 dst-nodes per bucket
#define BNODES 256
#define MAXB   512               // supports N <= 131072
#define CHUNK  4096              // edges per partition block

typedef _Float16 half8 __attribute__((ext_vector_type(8)));
typedef float  float4v __attribute__((ext_vector_type(4)));

// ---------------- fused setup: bucket_count | fp32->fp16 | weight transpose ----------------
__global__ __launch_bounds__(256) void setup_kernel(
    const int* __restrict__ dst, int* __restrict__ bcnt, int E, int PB,
    const float* __restrict__ h, __half* __restrict__ h16, int n4, int CB,
    const float* w0, const float* w1, const float* w2,
    const float* w3, const float* w4, const float* w5,
    __half* __restrict__ wT)
{
    __shared__ int cnt[MAXB];
    int b = blockIdx.x;
    if (b < PB) {
        // per-bucket edge counts
        for (int i = threadIdx.x; i < MAXB; i += 256) cnt[i] = 0;
        __syncthreads();
        int base = b * CHUNK;
        for (int i = threadIdx.x; i < CHUNK; i += 256) {
            int e = base + i;
            if (e < E) atomicAdd(&cnt[dst[e] >> BSHIFT], 1);
        }
        __syncthreads();
        for (int i = threadIdx.x; i < MAXB; i += 256)
            if (cnt[i]) atomicAdd(&bcnt[i], cnt[i]);
    } else if (b < PB + CB) {
        // fp32 -> fp16 feature conversion
        int i = (b - PB) * 256 + threadIdx.x;
        if (i < n4) {
            float4 v = ((const float4*)h)[i];
            union { uint2 u; __half2 h2[2]; } r;
            r.h2[0] = __floats2half2_rn(v.x, v.y);
            r.h2[1] = __floats2half2_rn(v.z, v.w);
            ((uint2*)h16)[i] = r.u;
        }
    } else {
        // weights: fp32 [in][out] -> f16 transposed [out][in]
        int bb = b - PB - CB;                 // 0..95
        int m = bb >> 4;
        int idx = ((bb & 15) << 8) | threadIdx.x;
        const float* src = m==0?w0 : m==1?w1 : m==2?w2 : m==3?w3 : m==4?w4 : w5;
        int o = idx >> 6, i = idx & 63;
        wT[m * 4096 + o * 64 + i] = __float2half(src[i * 64 + o]);
    }
}

// ---------------- Pass 2: scan bucket counts (1 block) ----------------
__global__ __launch_bounds__(512) void bucket_scan_kernel(
    const int* __restrict__ bcnt, int* __restrict__ boff, int* __restrict__ bcur,
    int NB, int E)
{
    __shared__ int s[512];
    int v = (threadIdx.x < (unsigned)NB) ? bcnt[threadIdx.x] : 0;
    s[threadIdx.x] = v;
    __syncthreads();
    for (int off = 1; off < 512; off <<= 1) {
        int t = (threadIdx.x >= (unsigned)off) ? s[threadIdx.x - off] : 0;
        __syncthreads();
        s[threadIdx.x] += t;
        __syncthreads();
    }
    if (threadIdx.x < (unsigned)NB) {
        int ex = s[threadIdx.x] - v;
        boff[threadIdx.x] = ex;
        bcur[threadIdx.x] = ex;
    }
    if (threadIdx.x == 0) boff[NB] = E;
}

// ---------------- Pass 3: partition edges into buckets ----------------
// Output word: src | (local_dst << 20)
__global__ __launch_bounds__(256) void partition_kernel(
    const int* __restrict__ src, const int* __restrict__ dst,
    int* __restrict__ bcur, int* __restrict__ pedge, int E)
{
    __shared__ int cnt[MAXB];
    __shared__ int sa[MAXB], sb[MAXB];
    __shared__ int gb[MAXB];
    __shared__ int lcur[MAXB];
    __shared__ int stage[CHUNK];
    __shared__ int tgt[CHUNK];

    for (int i = threadIdx.x; i < MAXB; i += 256) cnt[i] = 0;
    __syncthreads();

    int base = blockIdx.x * CHUNK;
    int vals[16];
    int bs[16];
#pragma unroll
    for (int i = 0; i < 16; i++) {
        int e = base + threadIdx.x + i * 256;
        bs[i] = -1;
        if (e < E) {
            int s_ = src[e];
            int d_ = dst[e];
            int b  = d_ >> BSHIFT;
            bs[i]  = b;
            vals[i] = s_ | ((d_ & (BNODES - 1)) << 20);
            atomicAdd(&cnt[b], 1);
        }
    }
    __syncthreads();

    for (int i = threadIdx.x; i < MAXB; i += 256) sa[i] = cnt[i];
    __syncthreads();
    int* cur = sa; int* nxt = sb;
    for (int off = 1; off < MAXB; off <<= 1) {
        for (int i = threadIdx.x; i < MAXB; i += 256)
            nxt[i] = cur[i] + ((i >= off) ? cur[i - off] : 0);
        __syncthreads();
        int* tmp = cur; cur = nxt; nxt = tmp;
    }
    for (int i = threadIdx.x; i < MAXB; i += 256) {
        int c = cnt[i];
        int lo = cur[i] - c;
        int gbase = c ? atomicAdd(&bcur[i], c) : 0;
        gb[i]   = gbase - lo;
        lcur[i] = lo;
    }
    __syncthreads();

#pragma unroll
    for (int i = 0; i < 16; i++) {
        if (bs[i] >= 0) {
            int pos = atomicAdd(&lcur[bs[i]], 1);
            stage[pos] = vals[i];
            tgt[pos]   = gb[bs[i]];
        }
    }
    __syncthreads();

    int cn = min(CHUNK, E - base);
    for (int i = threadIdx.x; i < cn; i += 256)
        pedge[tgt[i] + i] = stage[i];
}

// ---------------- Pass 4: per-bucket CSR build ----------------
__global__ __launch_bounds__(256) void buildcsr_kernel(
    const int* __restrict__ pedge, const int* __restrict__ boff,
    int* __restrict__ rowptr, int* __restrict__ csr_src, int N, int NB)
{
    __shared__ int hist[BNODES];
    __shared__ int scn[BNODES];
    __shared__ int lcur[BNODES];
    int b = blockIdx.x;
    int beg = boff[b], end = boff[b + 1];

    hist[threadIdx.x] = 0;
    __syncthreads();
    for (int e = beg + (int)threadIdx.x; e < end; e += 256)
        atomicAdd(&hist[pedge[e] >> 20], 1);
    __syncthreads();

    int v = hist[threadIdx.x];
    scn[threadIdx.x] = v;
    __syncthreads();
    for (int off = 1; off < 256; off <<= 1) {
        int t = (threadIdx.x >= (unsigned)off) ? scn[threadIdx.x - off] : 0;
        __syncthreads();
        scn[threadIdx.x] += t;
        __syncthreads();
    }
    int excl = scn[threadIdx.x] - v;

    int node = (b << BSHIFT) + threadIdx.x;
    if (node < N) rowptr[node] = beg + excl;
    if (b == NB - 1 && threadIdx.x == 0) rowptr[N] = boff[NB];
    lcur[threadIdx.x] = excl;
    __syncthreads();

    for (int e = beg + (int)threadIdx.x; e < end; e += 256) {
        int p  = pedge[e];
        int ld = p >> 20;
        int pos = atomicAdd(&lcur[ld], 1);
        csr_src[beg + pos] = p & 0xFFFFF;
    }
}

// ---------------- Fused layer: gather-mean -> MFMA sage -> MFMA lin ----------------
// Block = 64 nodes, 4 waves; wave w owns MFMA rows [16w,16w+16).
// Gather: lane = (node-octet, 16B slot); private half8 accumulators (pk_add),
// fp32 combine + /deg, mean -> LDS in A-layout.
// Stage 1: relu(mean@Wl + self@Wr + b1) -> LDS. Stage 2: @W2 + b2 -> global.
// Weights f16 transposed [out][in]; layouts as verified in round 7.
__global__ __launch_bounds__(256) void layer_kernel(
    const __half* __restrict__ x16,     // gather source (f16 rows)
    const __half* __restrict__ self16,  // self rows (f16) — same as x16 here
    const int* __restrict__ rowptr, const int* __restrict__ csr,
    const __half* __restrict__ wlT, const __half* __restrict__ wrT,
    const __half* __restrict__ w2T,
    const float* __restrict__ b1, const float* __restrict__ b2,
    float* __restrict__ out_f, __half* __restrict__ out_h,
    int n, int relu_out)
{
    __shared__ _Float16 smean[64][68];  // gathered means, A-layout re-entry
    __shared__ _Float16 s1[64][68];     // stage-1 output
    int wave = threadIdx.x >> 6;
    int lane = threadIdx.x & 63;
    int blockbase = blockIdx.x * 64;

    // ---- gather phase: 2 passes x 8 nodes per wave ----
    int s8 = lane & 7;
#pragma unroll
    for (int p = 0; p < 2; p++) {
        int nl = wave * 16 + p * 8 + (lane >> 3);
        int node = blockbase + nl;
        int beg = 0, end = 0;
        if (node < n) { beg = rowptr[node]; end = rowptr[node + 1]; }
        half8 a0 = 0, a1 = 0, a2 = 0, a3 = 0;
        int e = beg;
        for (; e + 3 < end; e += 4) {
            int i0 = csr[e], i1 = csr[e+1], i2 = csr[e+2], i3 = csr[e+3];
            a0 += ((const half8*)(x16 + (size_t)i0 * FEAT))[s8];
            a1 += ((const half8*)(x16 + (size_t)i1 * FEAT))[s8];
            a2 += ((const half8*)(x16 + (size_t)i2 * FEAT))[s8];
            a3 += ((const half8*)(x16 + (size_t)i3 * FEAT))[s8];
        }
        for (; e < end; e++)
            a0 += ((const half8*)(x16 + (size_t)csr[e] * FEAT))[s8];
        float inv = (end > beg) ? 1.0f / (float)(end - beg) : 0.0f;
        union { uint2 u2[2]; _Float16 h[8]; } o;
#pragma unroll
        for (int t = 0; t < 8; t++) {
            float f = ((float)a0[t] + (float)a1[t]) + ((float)a2[t] + (float)a3[t]);
            o.h[t] = (_Float16)(f * inv);
        }
        *(uint2*)&smean[nl][s8 * 8]     = o.u2[0];
        *(uint2*)&smean[nl][s8 * 8 + 4] = o.u2[1];
    }
    __syncthreads();

    // ---- MFMA phase ----
    int r = lane & 15;                  // A row / B-C col
    int q = lane >> 4;                  // quad
    int base = blockbase + wave * 16;

    // A-frags: mean from LDS, self from global
    union { uint2 u2[2]; half8 h; } Am0, Am1;
    {
        const _Float16* mp = &smean[wave * 16 + r][0];
        Am0.u2[0] = *(const uint2*)(mp + q * 8);
        Am0.u2[1] = *(const uint2*)(mp + q * 8 + 4);
        Am1.u2[0] = *(const uint2*)(mp + 32 + q * 8);
        Am1.u2[1] = *(const uint2*)(mp + 32 + q * 8 + 4);
    }
    int arow = min(base + r, n - 1);
    const half8* xrow = (const half8*)(self16 + (size_t)arow * FEAT);
    half8 Ax0 = xrow[q], Ax1 = xrow[4 + q];

    float4v acc[4];
#pragma unroll
    for (int c = 0; c < 4; c++) {
        float bv = b1[c * 16 + r];
        acc[c] = (float4v){bv, bv, bv, bv};
        const half8* bl = (const half8*)(wlT + (size_t)(c * 16 + r) * FEAT);
        const half8* br = (const half8*)(wrT + (size_t)(c * 16 + r) * FEAT);
        acc[c] = __builtin_amdgcn_mfma_f32_16x16x32_f16(Am0.h, bl[q],     acc[c], 0, 0, 0);
        acc[c] = __builtin_amdgcn_mfma_f32_16x16x32_f16(Am1.h, bl[4 + q], acc[c], 0, 0, 0);
        acc[c] = __builtin_amdgcn_mfma_f32_16x16x32_f16(Ax0,   br[q],     acc[c], 0, 0, 0);
        acc[c] = __builtin_amdgcn_mfma_f32_16x16x32_f16(Ax1,   br[4 + q], acc[c], 0, 0, 0);
    }
#pragma unroll
    for (int c = 0; c < 4; c++)
#pragma unroll
        for (int t = 0; t < 4; t++)
            s1[wave * 16 + q * 4 + t][c * 16 + r] = (_Float16)fmaxf(acc[c][t], 0.0f);
    __syncthreads();

    union { uint2 u2[2]; half8 h; } A2[2];
#pragma unroll
    for (int s = 0; s < 2; s++) {
        const _Float16* p = &s1[wave * 16 + r][s * 32 + q * 8];
        A2[s].u2[0] = *(const uint2*)p;
        A2[s].u2[1] = *(const uint2*)(p + 4);
    }

    float4v acc2[4];
#pragma unroll
    for (int c = 0; c < 4; c++) {
        float bv = b2[c * 16 + r];
        acc2[c] = (float4v){bv, bv, bv, bv};
        const half8* bw = (const half8*)(w2T + (size_t)(c * 16 + r) * FEAT);
        acc2[c] = __builtin_amdgcn_mfma_f32_16x16x32_f16(A2[0].h, bw[q],     acc2[c], 0, 0, 0);
        acc2[c] = __builtin_amdgcn_mfma_f32_16x16x32_f16(A2[1].h, bw[4 + q], acc2[c], 0, 0, 0);
    }

#pragma unroll
    for (int c = 0; c < 4; c++)
#pragma unroll
        for (int t = 0; t < 4; t++) {
            int gr = base + q * 4 + t;
            if (gr < n) {
                float v = acc2[c][t];
                if (relu_out) v = fmaxf(v, 0.0f);
                if (out_h) out_h[(size_t)gr * FEAT + c * 16 + r] = __float2half(v);
                else       out_f[(size_t)gr * FEAT + c * 16 + r] = v;
            }
        }
}

extern "C" void kernel_launch(void* const* d_in, const int* in_sizes, int n_in,
                              void* d_out, int out_size, void* d_ws, size_t ws_size,
                              hipStream_t stream) {
    const float* h      = (const float*)d_in[0];
    const int*   ei     = (const int*)d_in[1];
    const float* w1_l   = (const float*)d_in[2];
    const float* b1_l   = (const float*)d_in[3];
    const float* w1_r   = (const float*)d_in[4];
    const float* w_lin1 = (const float*)d_in[5];
    const float* b_lin1 = (const float*)d_in[6];
    const float* w2_l   = (const float*)d_in[7];
    const float* b2_l   = (const float*)d_in[8];
    const float* w2_r   = (const float*)d_in[9];
    const float* w_lin2 = (const float*)d_in[10];
    const float* b_lin2 = (const float*)d_in[11];

    const int N = in_sizes[0] / FEAT;
    const int E = in_sizes[1] / 2;
    const int* src  = ei;
    const int* dst_ = ei + E;

    const int NB = (N + BNODES - 1) >> BSHIFT;
    const int PB = (E + CHUNK - 1) / CHUNK;
    const int n4 = N * FEAT / 4;
    const int CB = (n4 + 255) / 256;
    const int tblk = (N + 63) / 64;

    // Workspace (float-indexed):
    // bcnt | boff | bcur | rowptr[N+1] | csr[E] | h16[N*32] | x2h[N*32] | wT[6*2048 fl] | pedge[E]
    size_t off = 0;
    int* bcnt   = (int*)d_ws + off; off += MAXB;
    int* boff   = (int*)d_ws + off; off += MAXB + 1;
    int* bcur   = (int*)d_ws + off; off += MAXB;
    off = (off + 3) & ~(size_t)3;
    int* rowptr = (int*)d_ws + off; off += (size_t)N + 1;
    off = (off + 3) & ~(size_t)3;
    int* csr    = (int*)d_ws + off; off += (size_t)E;
    off = (off + 3) & ~(size_t)3;
    __half* h16 = (__half*)((int*)d_ws + off); off += (size_t)N * FEAT / 2;
    __half* x2h = (__half*)((int*)d_ws + off); off += (size_t)N * FEAT / 2;
    __half* wT  = (__half*)((int*)d_ws + off); off += 6 * 2048;
    int* pedge  = (int*)d_ws + off; off += (size_t)E;

    // ---- preprocessing (once, reused by both conv layers) ----
    hipMemsetAsync(bcnt, 0, MAXB * sizeof(int), stream);
    setup_kernel<<<PB + CB + 96, 256, 0, stream>>>(
        dst_, bcnt, E, PB, h, h16, n4, CB,
        w1_l, w1_r, w_lin1, w2_l, w2_r, w_lin2, wT);
    bucket_scan_kernel<<<1, 512, 0, stream>>>(bcnt, boff, bcur, NB, E);
    partition_kernel<<<PB, 256, 0, stream>>>(src, dst_, bcur, pedge, E);
    buildcsr_kernel<<<NB, 256, 0, stream>>>(pedge, boff, rowptr, csr, N, NB);

    // ---- Layer 1: gather+conv1+lin1 (f16 in, f16 out) ----
    layer_kernel<<<tblk, 256, 0, stream>>>(h16, h16, rowptr, csr,
                                           wT + 0 * 4096, wT + 1 * 4096, wT + 2 * 4096,
                                           b1_l, b_lin1,
                                           (float*)nullptr, x2h, N, 1);

    // ---- Layer 2: gather+conv2+lin2 (f16 in, fp32 out) ----
    layer_kernel<<<tblk, 256, 0, stream>>>(x2h, x2h, rowptr, csr,
                                           wT + 3 * 4096, wT + 4 * 4096, wT + 5 * 4096,
                                           b2_l, b_lin2,
                                           (float*)d_out, (__half*)nullptr, N, 0);
}